// Round 10
// baseline (693.758 us; speedup 1.0000x reference)
//
#include <hip/hip_runtime.h>
#include <math.h>

#define NN   192     // N = state = OUT, grid size
#define NIN  64
#define NT   32
#define BLK  192     // 3 waves; thread tid owns global index tid
#define NW   3

typedef unsigned long long u64;
typedef unsigned int u32;

// ONE exchange per step: tagged u64 h-slots (r4-proven transport).
struct WS { u64 hslot[NN]; };   // (tag<<32)|bits(h_b)

#define REP48(M) M(0)M(1)M(2)M(3)M(4)M(5)M(6)M(7)M(8)M(9)M(10)M(11)M(12)M(13)M(14)M(15)M(16)M(17)M(18)M(19)M(20)M(21)M(22)M(23)M(24)M(25)M(26)M(27)M(28)M(29)M(30)M(31)M(32)M(33)M(34)M(35)M(36)M(37)M(38)M(39)M(40)M(41)M(42)M(43)M(44)M(45)M(46)M(47)
#define REP31(M) M(1)M(2)M(3)M(4)M(5)M(6)M(7)M(8)M(9)M(10)M(11)M(12)M(13)M(14)M(15)M(16)M(17)M(18)M(19)M(20)M(21)M(22)M(23)M(24)M(25)M(26)M(27)M(28)M(29)M(30)M(31)
#define SH31(A) A(31,30)A(30,29)A(29,28)A(28,27)A(27,26)A(26,25)A(25,24)A(24,23)A(23,22)A(22,21)A(21,20)A(20,19)A(19,18)A(18,17)A(17,16)A(16,15)A(15,14)A(14,13)A(13,12)A(12,11)A(11,10)A(10,9)A(9,8)A(8,7)A(7,6)A(6,5)A(5,4)A(4,3)A(3,2)A(2,1)

__device__ __forceinline__ u64 pack_h(float v, u32 tag) {
  return ((u64)tag << 32) | (u64)__float_as_uint(v);
}

__device__ __forceinline__ float tanh_fast(float x) {
  x = fminf(fmaxf(x, -15.f), 15.f);
  const float e = __expf(-2.f * x);
  return (1.f - e) * __builtin_amdgcn_rcpf(1.f + e);
}

__device__ __forceinline__ void publish(u64* p, u64 v) {
  __hip_atomic_store(p, v, __ATOMIC_RELAXED, __HIP_MEMORY_SCOPE_AGENT);
}

__device__ __forceinline__ float poll_h(u64* p, u32 tag) {
  u64 v; long g = 0;
  while (true) {
    v = __hip_atomic_load(p, __ATOMIC_RELAXED, __HIP_MEMORY_SCOPE_AGENT);
    if ((u32)(v >> 32) == tag) break;
    __builtin_amdgcn_s_sleep(1);
    if (++g > 30000000L) break;    // hang guard
  }
  return __uint_as_float((u32)v);
}

// K-way fused block reduction; ONE __syncthreads inside.
template <int K>
__device__ __forceinline__ void block_reduceK(float* v, float (*red)[NW], int w, int l) {
  #pragma unroll
  for (int o = 32; o > 0; o >>= 1) {
    #pragma unroll
    for (int q = 0; q < K; ++q) v[q] += __shfl_xor(v[q], o, 64);
  }
  if (l == 0) {
    #pragma unroll
    for (int q = 0; q < K; ++q) red[q][w] = v[q];
  }
  __syncthreads();
  #pragma unroll
  for (int q = 0; q < K; ++q) v[q] = red[q][0] + red[q][1] + red[q][2];
}

extern "C" __global__ void __launch_bounds__(BLK, 1)
force_persistent(const float* __restrict__ x,   const float* __restrict__ y,
                 const float* __restrict__ Win, const float* __restrict__ Wrec,
                 const float* __restrict__ Wout,const float* __restrict__ a0,
                 const float* __restrict__ Pout,const float* __restrict__ Pgg,
                 float* __restrict__ out, WS* __restrict__ ws)
{
  const int b   = blockIdx.x;
  const int tid = threadIdx.x;
  const int w   = tid >> 6;
  const int l   = tid & 63;

  __shared__ __align__(16) float hsS[NN];
  __shared__ float xwS[NT];
  __shared__ float cS[64];      // c_s at [32+s], zeros below
  __shared__ float rS[64];      // rden_s (per-block) at [32+s]
  __shared__ float redA[33][NW];
  __shared__ float redB[31][NW];
  __shared__ float redC[1][NW];

  // ---- W_out column `tid` in registers (coalesced per-j loads) ----
  #define W0D(r) float4 w0_##r;
  REP48(W0D)
  #define W0L(r) w0_##r = make_float4(Wout[(4*(r)+0)*NN+tid], Wout[(4*(r)+1)*NN+tid], \
                                      Wout[(4*(r)+2)*NN+tid], Wout[(4*(r)+3)*NN+tid]);
  REP48(W0L)

  float wrt   = Wrec[tid * NN + b];   // W_rec[tid][b], kept current locally
  float y_cur = y[tid];
  const float alP = Pout[0];          // P_output = alP * I
  const float alG = Pgg[0];           // each P_GG slice = alG * I
  float a_run = a0[b];

  // histories (named regs, shifted -> all-static indices); zero-init = auto-predication
  #define HDECL(j) float kh##j = 0.f, eh##j = 0.f, ph##j = 0.f;
  REP31(HDECL)

  if (tid < 64) { cS[tid] = 0.f; rS[tid] = 0.f; }

  // xw[t] = (x_t @ W_in)[b] via wave0
  if (w == 0) {
    const float wv = Win[l * NN + b];
    float c[NT];
    #pragma unroll
    for (int t2 = 0; t2 < NT; ++t2) c[t2] = x[t2 * NIN + l] * wv;
    #pragma unroll
    for (int o = 32; o > 0; o >>= 1) {
      #pragma unroll
      for (int t2 = 0; t2 < NT; ++t2) c[t2] += __shfl_xor(c[t2], o, 64);
    }
    if (l == 0) {
      #pragma unroll
      for (int t2 = 0; t2 < NT; ++t2) xwS[t2] = c[t2];
    }
  }

  // ---- prologue: h_0 = tanh(0.9 a0 + 0.1 (tanh(a0)@W_rec + xw_0)) ----
  {
    float v0[1] = { tanh_fast(a0[tid]) * wrt };
    block_reduceK<1>(v0, redC, w, l);      // barrier also fences cS/rS/xwS init
    a_run = 0.9f * a_run + 0.1f * (v0[0] + xwS[0]);
    if (tid == 0) publish(&ws->hslot[b], pack_h(tanh_fast(a_run), 1u));
  }

  #pragma unroll 1
  for (int t = 0; t < NT; ++t) {
    // ---- the ONLY global exchange: poll h_t ----
    const float h_own = poll_h(&ws->hslot[tid], (u32)(t + 1));
    hsS[tid] = h_own;

    // ---- products for fused reduces (own-element only; no hsS reads) ----
    float va[33], vb[31];
    va[0] = h_own * wrt;                    // ssum partial (W_r^{t-1} current)
    va[1] = h_own * h_own;                  // |h|^2
    #define PBA(j) va[1+(j)] = kh##j * h_own;    // beta_j = k^{t-j} . h
    REP31(PBA)
    #define PBB(j) vb[(j)-1] = ph##j * h_own;    // delta_j = p^{t-j} . h
    REP31(PBB)
    block_reduceK<33>(va, redA, w, l);      // barrier #1 (also fences hsS)

    // ---- z0 = W_o^0[:,tid] . h  (ILP-overlaps redB's shuffle chains) ----
    const float4* h4 = (const float4*)hsS;
    float4 zac = make_float4(0.f, 0.f, 0.f, 0.f);
    #define Z0M(r) { const float4 hv = h4[r]; \
                     zac.x += w0_##r.x*hv.x; zac.y += w0_##r.y*hv.y; \
                     zac.z += w0_##r.z*hv.z; zac.w += w0_##r.w*hv.w; }
    REP48(Z0M)
    block_reduceK<31>(vb, redB, w, l);      // barrier #2

    // ---- history corrections (all local) ----
    const float hh = va[1];
    float kacc = alP * h_own, hk = alP * hh;
    float zc   = (zac.x + zac.y) + (zac.z + zac.w);
    float pacc = alG * h_own, hPh = alG * hh;
    #define CORRA(j) { const float bj = va[1+(j)]; const float gj = cS[32+t-(j)] * bj; \
                       kacc = fmaf(-gj, kh##j, kacc); hk = fmaf(-gj, bj, hk); \
                       zc   = fmaf(-gj, eh##j, zc); }
    REP31(CORRA)
    #define CORRB(j) { const float dj = vb[(j)-1]; const float rj = rS[32+t-(j)] * dj; \
                       pacc = fmaf(-rj, ph##j, pacc); hPh = fmaf(-rj, dj, hPh); }
    REP31(CORRB)

    const float c_t   = 1.f / (1.f + hk);     // global, identical in all blocks
    const float rden  = 1.f / (1.f + hPh);    // per-block (slice b)
    const float e_own = zc - y_cur;

    if (b == 0) out[t * NN + tid] = zc;       // z IS the output row
    if (t == NT - 1) break;

    if (tid == 0) { cS[32 + t] = c_t; rS[32 + t] = rden; }

    // ---- corr2 = sum_i h_i p_i e_i (W_r step-t rank-1 folded into a-update) ----
    float u[1] = { h_own * pacc * e_own };
    block_reduceK<1>(u, redC, w, l);          // barrier #3 (fences cS/rS writes)

    a_run = 0.9f * a_run + 0.1f * (va[0] - rden * u[0] + xwS[t + 1]);
    if (tid == 0) publish(&ws->hslot[b], pack_h(tanh_fast(a_run), (u32)(t + 2)));

    // ---- off-critical-path: history shift, W_r row update, y prefetch ----
    #define SH3(a2,b2) kh##a2 = kh##b2; eh##a2 = eh##b2; ph##a2 = ph##b2;
    SH31(SH3)
    kh1 = kacc; eh1 = e_own; ph1 = pacc;
    wrt = fmaf(-rden * pacc, e_own, wrt);     // W_r[tid][b] -= rden p_tid e_tid
    y_cur = y[(t + 1) * NN + tid];
  }
}

extern "C" void kernel_launch(void* const* d_in, const int* in_sizes, int n_in,
                              void* d_out, int out_size, void* d_ws, size_t ws_size,
                              hipStream_t stream) {
  const float* x    = (const float*)d_in[0];
  const float* y    = (const float*)d_in[1];
  const float* Win  = (const float*)d_in[2];
  const float* Wrec = (const float*)d_in[3];
  const float* Wout = (const float*)d_in[4];
  const float* a0   = (const float*)d_in[5];
  const float* Pout = (const float*)d_in[6];
  const float* Pgg  = (const float*)d_in[7];
  float* out = (float*)d_out;
  WS* ws = (WS*)d_ws;
  (void)in_sizes; (void)n_in; (void)out_size; (void)ws_size;

  // reset h tags each call (graph replays must not see stale tags)
  hipMemsetAsync(ws, 0, sizeof(WS), stream);
  force_persistent<<<NN, BLK, 0, stream>>>(x, y, Win, Wrec, Wout, a0, Pout, Pgg, out, ws);
}

// Round 11
// 313.236 us; speedup vs baseline: 2.2148x; 2.2148x over previous
//
#include <hip/hip_runtime.h>
#include <math.h>

#define NN   192     // N = state = OUT, grid size
#define NIN  64
#define NT   32
#define BLK  192     // 3 waves; thread tid owns global index tid
#define NW   3

typedef unsigned long long u64;
typedef unsigned int u32;

// ONE exchange per step: tagged u64 h-slots (r4-proven transport).
struct WS { u64 hslot[NN]; };   // (tag<<32)|bits(h_b)

#define REP48(M) M(0)M(1)M(2)M(3)M(4)M(5)M(6)M(7)M(8)M(9)M(10)M(11)M(12)M(13)M(14)M(15)M(16)M(17)M(18)M(19)M(20)M(21)M(22)M(23)M(24)M(25)M(26)M(27)M(28)M(29)M(30)M(31)M(32)M(33)M(34)M(35)M(36)M(37)M(38)M(39)M(40)M(41)M(42)M(43)M(44)M(45)M(46)M(47)
#define REP31(M) M(1)M(2)M(3)M(4)M(5)M(6)M(7)M(8)M(9)M(10)M(11)M(12)M(13)M(14)M(15)M(16)M(17)M(18)M(19)M(20)M(21)M(22)M(23)M(24)M(25)M(26)M(27)M(28)M(29)M(30)M(31)
#define SH31(A) A(31,30)A(30,29)A(29,28)A(28,27)A(27,26)A(26,25)A(25,24)A(24,23)A(23,22)A(22,21)A(21,20)A(20,19)A(19,18)A(18,17)A(17,16)A(16,15)A(15,14)A(14,13)A(13,12)A(12,11)A(11,10)A(10,9)A(9,8)A(8,7)A(7,6)A(6,5)A(5,4)A(4,3)A(3,2)A(2,1)

__device__ __forceinline__ u64 pack_h(float v, u32 tag) {
  return ((u64)tag << 32) | (u64)__float_as_uint(v);
}

__device__ __forceinline__ float tanh_fast(float x) {
  x = fminf(fmaxf(x, -15.f), 15.f);
  const float e = __expf(-2.f * x);
  return (1.f - e) * __builtin_amdgcn_rcpf(1.f + e);
}

__device__ __forceinline__ void publish(u64* p, u64 v) {
  __hip_atomic_store(p, v, __ATOMIC_RELAXED, __HIP_MEMORY_SCOPE_AGENT);
}

__device__ __forceinline__ float poll_h(u64* p, u32 tag) {
  u64 v; long g = 0;
  while (true) {
    v = __hip_atomic_load(p, __ATOMIC_RELAXED, __HIP_MEMORY_SCOPE_AGENT);
    if ((u32)(v >> 32) == tag) break;
    __builtin_amdgcn_s_sleep(1);
    if (++g > 30000000L) break;    // hang guard
  }
  return __uint_as_float((u32)v);
}

// K-way fused block reduction; ONE __syncthreads inside.
template <int K>
__device__ __forceinline__ void block_reduceK(float* v, float (*red)[NW], int w, int l) {
  #pragma unroll
  for (int o = 32; o > 0; o >>= 1) {
    #pragma unroll
    for (int q = 0; q < K; ++q) v[q] += __shfl_xor(v[q], o, 64);
  }
  if (l == 0) {
    #pragma unroll
    for (int q = 0; q < K; ++q) red[q][w] = v[q];
  }
  __syncthreads();
  #pragma unroll
  for (int q = 0; q < K; ++q) v[q] = red[q][0] + red[q][1] + red[q][2];
}

extern "C" __global__ void __launch_bounds__(BLK, 1)
force_persistent(const float* __restrict__ x,   const float* __restrict__ y,
                 const float* __restrict__ Win, const float* __restrict__ Wrec,
                 const float* __restrict__ Wout,const float* __restrict__ a0,
                 const float* __restrict__ Pout,const float* __restrict__ Pgg,
                 float* __restrict__ out, WS* __restrict__ ws)
{
  const int b   = blockIdx.x;
  const int tid = threadIdx.x;
  const int w   = tid >> 6;
  const int l   = tid & 63;

  __shared__ __align__(16) float hsS[NN];
  __shared__ float xwS[NT];
  __shared__ float cS[64];      // c_s at [32+s], zeros below
  __shared__ float rS[64];      // rden_s (per-block) at [32+s]
  __shared__ float redA[64][NW];
  __shared__ float redC[1][NW];

  float wrt   = Wrec[tid * NN + b];   // W_rec[tid][b], kept current locally
  float y_cur = y[tid];
  const float alP = Pout[0];          // P_output = alP * I
  const float alG = Pgg[0];           // each P_GG slice = alG * I
  float a_run = a0[b];

  // histories (named regs, shifted -> all-static indices); zero = auto-predication
  #define HDECL(j) float kh##j = 0.f, eh##j = 0.f, ph##j = 0.f;
  REP31(HDECL)

  if (tid < 64) { cS[tid] = 0.f; rS[tid] = 0.f; }

  // xw[t] = (x_t @ W_in)[b] via wave0
  if (w == 0) {
    const float wv = Win[l * NN + b];
    float c[NT];
    #pragma unroll
    for (int t2 = 0; t2 < NT; ++t2) c[t2] = x[t2 * NIN + l] * wv;
    #pragma unroll
    for (int o = 32; o > 0; o >>= 1) {
      #pragma unroll
      for (int t2 = 0; t2 < NT; ++t2) c[t2] += __shfl_xor(c[t2], o, 64);
    }
    if (l == 0) {
      #pragma unroll
      for (int t2 = 0; t2 < NT; ++t2) xwS[t2] = c[t2];
    }
  }

  // ---- prologue: h_0 = tanh(0.9 a0 + 0.1 (tanh(a0)@W_rec + xw_0)) ----
  {
    float v0[1] = { tanh_fast(a0[tid]) * wrt };
    block_reduceK<1>(v0, redC, w, l);      // barrier also fences cS/rS/xwS init
    a_run = 0.9f * a_run + 0.1f * (v0[0] + xwS[0]);
    if (tid == 0) publish(&ws->hslot[b], pack_h(tanh_fast(a_run), 1u));
  }

  #pragma unroll 1
  for (int t = 0; t < NT; ++t) {
    // ---- the ONLY global exchange: poll h_t ----
    const float h_own = poll_h(&ws->hslot[tid], (u32)(t + 1));
    hsS[tid] = h_own;

    // ---- ONE fused 64-wide reduce: ssum, |h|^2, 31 betas, 31 deltas ----
    float va[64];
    va[0] = h_own * wrt;                    // h . W_r^{t-1} col b
    va[1] = h_own * h_own;                  // |h|^2
    #define PBA(j) va[1+(j)] = kh##j * h_own;      // beta_j  = k^{t-j} . h
    REP31(PBA)
    #define PBB(j) va[32+(j)] = ph##j * h_own;     // delta_j = p^{t-j} . h
    REP31(PBB)
    block_reduceK<64>(va, redA, w, l);      // barrier #1 (also fences hsS)

    // ---- z0 = W_o^0[:,tid] . h  — streamed from L2-resident W_out ----
    const float4* h4 = (const float4*)hsS;
    float4 zac = make_float4(0.f, 0.f, 0.f, 0.f);
    #define Z0M(r) { const float4 hv = h4[r]; \
                     zac.x += Wout[(4*(r)+0)*NN+tid]*hv.x; \
                     zac.y += Wout[(4*(r)+1)*NN+tid]*hv.y; \
                     zac.z += Wout[(4*(r)+2)*NN+tid]*hv.z; \
                     zac.w += Wout[(4*(r)+3)*NN+tid]*hv.w; }
    REP48(Z0M)

    // ---- history corrections (all block-local) ----
    const float hh = va[1];
    float kacc = alP * h_own, hk = alP * hh;
    float zc   = (zac.x + zac.y) + (zac.z + zac.w);
    float pacc = alG * h_own, hPh = alG * hh;
    #define CORRA(j) { const float bj = va[1+(j)]; const float gj = cS[32+t-(j)] * bj; \
                       kacc = fmaf(-gj, kh##j, kacc); hk = fmaf(-gj, bj, hk); \
                       zc   = fmaf(-gj, eh##j, zc); }
    REP31(CORRA)
    #define CORRB(j) { const float dj = va[32+(j)]; const float rj = rS[32+t-(j)] * dj; \
                       pacc = fmaf(-rj, ph##j, pacc); hPh = fmaf(-rj, dj, hPh); }
    REP31(CORRB)

    const float c_t   = 1.f / (1.f + hk);     // global (identical in all blocks)
    const float rden  = 1.f / (1.f + hPh);    // per-block (slice b)
    const float e_own = zc - y_cur;

    if (b == 0) out[t * NN + tid] = zc;       // z IS the output row
    if (t == NT - 1) break;

    if (tid == 0) { cS[32 + t] = c_t; rS[32 + t] = rden; }

    // ---- corr2 = sum_i h_i p_i e_i (W_r^t rank-1 folded into a-update) ----
    float u[1] = { h_own * pacc * e_own };
    block_reduceK<1>(u, redC, w, l);          // barrier #2 (fences cS/rS writes)

    a_run = 0.9f * a_run + 0.1f * (va[0] - rden * u[0] + xwS[t + 1]);
    if (tid == 0) publish(&ws->hslot[b], pack_h(tanh_fast(a_run), (u32)(t + 2)));

    // ---- off-critical-path: history shift, W_r row update, y prefetch ----
    #define SH3(a2,b2) kh##a2 = kh##b2; eh##a2 = eh##b2; ph##a2 = ph##b2;
    SH31(SH3)
    kh1 = kacc; eh1 = e_own; ph1 = pacc;
    wrt = fmaf(-rden * pacc, e_own, wrt);     // W_r[tid][b] -= rden p_tid e_tid
    y_cur = y[(t + 1) * NN + tid];
  }
}

extern "C" void kernel_launch(void* const* d_in, const int* in_sizes, int n_in,
                              void* d_out, int out_size, void* d_ws, size_t ws_size,
                              hipStream_t stream) {
  const float* x    = (const float*)d_in[0];
  const float* y    = (const float*)d_in[1];
  const float* Win  = (const float*)d_in[2];
  const float* Wrec = (const float*)d_in[3];
  const float* Wout = (const float*)d_in[4];
  const float* a0   = (const float*)d_in[5];
  const float* Pout = (const float*)d_in[6];
  const float* Pgg  = (const float*)d_in[7];
  float* out = (float*)d_out;
  WS* ws = (WS*)d_ws;
  (void)in_sizes; (void)n_in; (void)out_size; (void)ws_size;

  // reset h tags each call (graph replays must not see stale tags)
  hipMemsetAsync(ws, 0, sizeof(WS), stream);
  force_persistent<<<NN, BLK, 0, stream>>>(x, y, Win, Wrec, Wout, a0, Pout, Pgg, out, ws);
}

// Round 12
// 231.703 us; speedup vs baseline: 2.9942x; 1.3519x over previous
//
#include <hip/hip_runtime.h>
#include <math.h>

#define NN   192     // N = state = OUT, grid size
#define NIN  64
#define NT   32
#define BLK  192     // 3 waves; thread tid owns global index tid
#define NW   3
#define HPAD 193     // LDS row pad: stride 193 floats -> bank-conflict-free

typedef unsigned long long u64;
typedef unsigned int u32;

// ONE exchange per step: tagged u64 h-slots (r4-proven transport).
struct WS { u64 hslot[NN]; };   // (tag<<32)|bits(h_b)

#define REP48(M) M(0)M(1)M(2)M(3)M(4)M(5)M(6)M(7)M(8)M(9)M(10)M(11)M(12)M(13)M(14)M(15)M(16)M(17)M(18)M(19)M(20)M(21)M(22)M(23)M(24)M(25)M(26)M(27)M(28)M(29)M(30)M(31)M(32)M(33)M(34)M(35)M(36)M(37)M(38)M(39)M(40)M(41)M(42)M(43)M(44)M(45)M(46)M(47)
#define REP31(M) M(1)M(2)M(3)M(4)M(5)M(6)M(7)M(8)M(9)M(10)M(11)M(12)M(13)M(14)M(15)M(16)M(17)M(18)M(19)M(20)M(21)M(22)M(23)M(24)M(25)M(26)M(27)M(28)M(29)M(30)M(31)

__device__ __forceinline__ u64 pack_h(float v, u32 tag) {
  return ((u64)tag << 32) | (u64)__float_as_uint(v);
}

__device__ __forceinline__ float tanh_fast(float x) {
  x = fminf(fmaxf(x, -15.f), 15.f);
  const float e = __expf(-2.f * x);
  return (1.f - e) * __builtin_amdgcn_rcpf(1.f + e);
}

__device__ __forceinline__ void publish(u64* p, u64 v) {
  __hip_atomic_store(p, v, __ATOMIC_RELAXED, __HIP_MEMORY_SCOPE_AGENT);
}

__device__ __forceinline__ float poll_h(u64* p, u32 tag) {
  u64 v; long g = 0;
  while (true) {
    v = __hip_atomic_load(p, __ATOMIC_RELAXED, __HIP_MEMORY_SCOPE_AGENT);
    if ((u32)(v >> 32) == tag) break;
    __builtin_amdgcn_s_sleep(1);
    if (++g > 30000000L) break;    // hang guard
  }
  return __uint_as_float((u32)v);
}

// K-way fused block reduction; ONE __syncthreads inside.
template <int K>
__device__ __forceinline__ void block_reduceK(float* v, float (*red)[NW], int w, int l) {
  #pragma unroll
  for (int o = 32; o > 0; o >>= 1) {
    #pragma unroll
    for (int q = 0; q < K; ++q) v[q] += __shfl_xor(v[q], o, 64);
  }
  if (l == 0) {
    #pragma unroll
    for (int q = 0; q < K; ++q) red[q][w] = v[q];
  }
  __syncthreads();
  #pragma unroll
  for (int q = 0; q < K; ++q) v[q] = red[q][0] + red[q][1] + red[q][2];
}

extern "C" __global__ void __launch_bounds__(BLK, 1)
force_persistent(const float* __restrict__ x,   const float* __restrict__ y,
                 const float* __restrict__ Win, const float* __restrict__ Wrec,
                 const float* __restrict__ Wout,const float* __restrict__ a0,
                 const float* __restrict__ Pout,const float* __restrict__ Pgg,
                 float* __restrict__ out, WS* __restrict__ ws)
{
  const int b   = blockIdx.x;
  const int tid = threadIdx.x;
  const int w   = tid >> 6;
  const int l   = tid & 63;

  // hist rows: [0..30] k-history slots, [31..61] p-history slots,
  //            [62] copy of h (for |h|^2), [63] zeros.
  __shared__ float hist[64][HPAD];     // 49.4 KB
  __shared__ float ehL [31][HPAD];     // 23.9 KB
  __shared__ __align__(16) float hsS[NN];
  __shared__ float ldsB[64][5];        // partials, pad 5 (gcd(5,32)=1)
  __shared__ float ldsF[64];           // finalized dot products
  __shared__ float cS[64];             // c_s at [32+s], zeros below
  __shared__ float rS[64];             // rden_s at [32+s]
  __shared__ float xwS[NT];
  __shared__ float red2[2][NW];

  // ---- zero-init LDS state ----
  for (int i = tid; i < 64 * HPAD; i += BLK) (&hist[0][0])[i] = 0.f;
  for (int i = tid; i < 31 * HPAD; i += BLK) (&ehL[0][0])[i]  = 0.f;
  if (tid < 64) { cS[tid] = 0.f; rS[tid] = 0.f; }

  // xw[t] = (x_t @ W_in)[b] via wave0
  if (w == 0) {
    const float wv = Win[l * NN + b];
    float c[NT];
    #pragma unroll
    for (int t2 = 0; t2 < NT; ++t2) c[t2] = x[t2 * NIN + l] * wv;
    #pragma unroll
    for (int o = 32; o > 0; o >>= 1) {
      #pragma unroll
      for (int t2 = 0; t2 < NT; ++t2) c[t2] += __shfl_xor(c[t2], o, 64);
    }
    if (l == 0) {
      #pragma unroll
      for (int t2 = 0; t2 < NT; ++t2) xwS[t2] = c[t2];
    }
  }

  float wrt   = Wrec[tid * NN + b];   // W_rec[tid][b], kept current locally
  float y_cur = y[tid];
  const float alP = Pout[0];          // P_output = alP * I
  const float alG = Pgg[0];           // each P_GG slice = alG * I
  float a_run = a0[b];

  // ---- prologue: h_0 ----
  {
    float v0[1] = { tanh_fast(a0[tid]) * wrt };
    block_reduceK<1>(v0, red2, w, l);      // barrier also fences LDS init
    a_run = 0.9f * a_run + 0.1f * (v0[0] + xwS[0]);
    if (tid == 0) publish(&ws->hslot[b], pack_h(tanh_fast(a_run), 1u));
  }

  // reducer thread mapping (constant over steps)
  const int qq    = tid & 63;
  const int chunk = tid >> 6;
  const int jeff  = (qq < 31) ? (qq + 1) : (qq - 30);   // history age for this q

  #pragma unroll 1
  for (int t = 0; t < NT; ++t) {
    // ---- the ONLY global exchange: poll h_t ----
    const float h_own = poll_h(&ws->hslot[tid], (u32)(t + 1));
    hsS[tid] = h_own;
    hist[62][tid] = h_own;               // row 62 => ldsF[62] = |h|^2
    __syncthreads();                     // barrier A

    // ---- z0 = W_o^0[:,tid].h — L2-streamed; hsS reads are wave-broadcast ----
    const float4* h4 = (const float4*)hsS;
    float4 zac = make_float4(0.f, 0.f, 0.f, 0.f);
    #define Z0M(r) { const float4 hv = h4[r]; \
                     zac.x += Wout[(4*(r)+0)*NN+tid]*hv.x; \
                     zac.y += Wout[(4*(r)+1)*NN+tid]*hv.y; \
                     zac.z += Wout[(4*(r)+2)*NN+tid]*hv.z; \
                     zac.w += Wout[(4*(r)+3)*NN+tid]*hv.w; }
    REP48(Z0M)

    // ---- distributed reduce: thread (qq,chunk) -> 64-elem partial of dot qq ----
    {
      int s = t - jeff; if (s < 0) s += 31;
      int row = (qq < 31) ? s : (31 + s);
      if (qq >= 62) row = qq;            // 62: h-copy, 63: zeros
      const float* hr = &hist[row][chunk * 64];
      const float* hc = &hsS[chunk * 64];
      float p0 = 0.f, p1 = 0.f, p2 = 0.f, p3 = 0.f;
      #pragma unroll
      for (int i = 0; i < 64; i += 4) {
        p0 = fmaf(hr[i + 0], hc[i + 0], p0);
        p1 = fmaf(hr[i + 1], hc[i + 1], p1);
        p2 = fmaf(hr[i + 2], hc[i + 2], p2);
        p3 = fmaf(hr[i + 3], hc[i + 3], p3);
      }
      ldsB[qq][chunk] = (p0 + p1) + (p2 + p3);
    }
    __syncthreads();                     // barrier B
    if (tid < 64) ldsF[tid] = ldsB[tid][0] + ldsB[tid][1] + ldsB[tid][2];
    __syncthreads();                     // barrier C

    // ---- history corrections (broadcast ldsF/cS/rS + per-lane hist/ehL) ----
    const float hh = ldsF[62];
    float zc   = (zac.x + zac.y) + (zac.z + zac.w);
    float kacc = alP * h_own, hk = alP * hh;
    float pacc = alG * h_own, hPh = alG * hh;
    #define CORRA(j) { int sj = t - (j); if (sj < 0) sj += 31; \
                       const float bj = ldsF[(j)-1]; const float gj = cS[32+t-(j)] * bj; \
                       kacc = fmaf(-gj, hist[sj][tid], kacc); hk = fmaf(-gj, bj, hk); \
                       zc   = fmaf(-gj, ehL[sj][tid], zc); }
    REP31(CORRA)
    #define CORRB(j) { int sj = t - (j); if (sj < 0) sj += 31; \
                       const float dj = ldsF[30+(j)]; const float rj = rS[32+t-(j)] * dj; \
                       pacc = fmaf(-rj, hist[31+sj][tid], pacc); hPh = fmaf(-rj, dj, hPh); }
    REP31(CORRB)

    const float c_t   = 1.f / (1.f + hk);     // global (identical in all blocks)
    const float rden  = 1.f / (1.f + hPh);    // per-block (slice b)
    const float e_own = zc - y_cur;

    if (b == 0) out[t * NN + tid] = zc;       // z IS the output row
    if (t == NT - 1) break;

    if (tid == 0) { cS[32 + t] = c_t; rS[32 + t] = rden; }

    // ---- tiny 2-wide butterfly: ssum = h.W_r^{t-1}, corr2 = sum h p e ----
    float u[2] = { h_own * wrt, h_own * pacc * e_own };
    block_reduceK<2>(u, red2, w, l);          // barrier D (fences CORR reads)

    a_run = 0.9f * a_run + 0.1f * (u[0] - rden * u[1] + xwS[t + 1]);
    if (tid == 0) publish(&ws->hslot[b], pack_h(tanh_fast(a_run), (u32)(t + 2)));

    // ---- end-of-step: circular history writes (fenced by next barrier A) ----
    const int sw = t % 31;                    // t <= 30 here
    hist[sw][tid]      = kacc;
    hist[31 + sw][tid] = pacc;
    ehL[sw][tid]       = e_own;
    wrt = fmaf(-rden * pacc, e_own, wrt);     // W_r[tid][b] -= rden p_tid e_tid
    y_cur = y[(t + 1) * NN + tid];
  }
}

extern "C" void kernel_launch(void* const* d_in, const int* in_sizes, int n_in,
                              void* d_out, int out_size, void* d_ws, size_t ws_size,
                              hipStream_t stream) {
  const float* x    = (const float*)d_in[0];
  const float* y    = (const float*)d_in[1];
  const float* Win  = (const float*)d_in[2];
  const float* Wrec = (const float*)d_in[3];
  const float* Wout = (const float*)d_in[4];
  const float* a0   = (const float*)d_in[5];
  const float* Pout = (const float*)d_in[6];
  const float* Pgg  = (const float*)d_in[7];
  float* out = (float*)d_out;
  WS* ws = (WS*)d_ws;
  (void)in_sizes; (void)n_in; (void)out_size; (void)ws_size;

  // reset h tags each call (graph replays must not see stale tags)
  hipMemsetAsync(ws, 0, sizeof(WS), stream);
  force_persistent<<<NN, BLK, 0, stream>>>(x, y, Win, Wrec, Wout, a0, Pout, Pgg, out, ws);
}

// Round 13
// 198.800 us; speedup vs baseline: 3.4897x; 1.1655x over previous
//
#include <hip/hip_runtime.h>
#include <math.h>

#define NN    192    // N = state = OUT, grid size
#define NIN   64
#define NT    32
#define BLK   192    // 3 waves; thread tid owns global index tid
#define NW    3
#define HPAD  193    // LDS row stride (odd -> banks spread for row-varying reads)
#define HROWS 62     // rows 0..30 = zeros (ages j>t), row 31+s = step-s history

typedef unsigned long long u64;
typedef unsigned int u32;

// ONE exchange per step: tagged u64 h-slots (r4-proven transport).
struct WS { u64 hslot[NN]; };   // (tag<<32)|bits(h_b)

#define REP48(M) M(0)M(1)M(2)M(3)M(4)M(5)M(6)M(7)M(8)M(9)M(10)M(11)M(12)M(13)M(14)M(15)M(16)M(17)M(18)M(19)M(20)M(21)M(22)M(23)M(24)M(25)M(26)M(27)M(28)M(29)M(30)M(31)M(32)M(33)M(34)M(35)M(36)M(37)M(38)M(39)M(40)M(41)M(42)M(43)M(44)M(45)M(46)M(47)
#define REP31(M) M(1)M(2)M(3)M(4)M(5)M(6)M(7)M(8)M(9)M(10)M(11)M(12)M(13)M(14)M(15)M(16)M(17)M(18)M(19)M(20)M(21)M(22)M(23)M(24)M(25)M(26)M(27)M(28)M(29)M(30)M(31)

__device__ __forceinline__ u64 pack_h(float v, u32 tag) {
  return ((u64)tag << 32) | (u64)__float_as_uint(v);
}

__device__ __forceinline__ float tanh_fast(float x) {
  x = fminf(fmaxf(x, -15.f), 15.f);
  const float e = __expf(-2.f * x);
  return (1.f - e) * __builtin_amdgcn_rcpf(1.f + e);
}

__device__ __forceinline__ void publish(u64* p, u64 v) {
  __hip_atomic_store(p, v, __ATOMIC_RELAXED, __HIP_MEMORY_SCOPE_AGENT);
}

__device__ __forceinline__ float poll_h(u64* p, u32 tag) {
  u64 v; long g = 0;
  while (true) {
    v = __hip_atomic_load(p, __ATOMIC_RELAXED, __HIP_MEMORY_SCOPE_AGENT);
    if ((u32)(v >> 32) == tag) break;
    __builtin_amdgcn_s_sleep(1);
    if (++g > 30000000L) break;    // hang guard
  }
  return __uint_as_float((u32)v);
}

// 1-wide block butterfly reduction; ONE __syncthreads inside.
__device__ __forceinline__ float block_reduce1(float v, float (*red)[NW], int w, int l) {
  #pragma unroll
  for (int o = 32; o > 0; o >>= 1) v += __shfl_xor(v, o, 64);
  if (l == 0) red[0][w] = v;
  __syncthreads();
  return red[0][0] + red[0][1] + red[0][2];
}

extern "C" __global__ void __launch_bounds__(BLK, 1)
force_persistent(const float* __restrict__ x,   const float* __restrict__ y,
                 const float* __restrict__ Win, const float* __restrict__ Wrec,
                 const float* __restrict__ Wout,const float* __restrict__ a0,
                 const float* __restrict__ Pout,const float* __restrict__ Pgg,
                 float* __restrict__ out, WS* __restrict__ ws)
{
  const int b   = blockIdx.x;
  const int tid = threadIdx.x;
  const int w   = tid >> 6;
  const int l   = tid & 63;

  __shared__ float khist[HROWS][HPAD];   // k^s at row 31+s
  __shared__ float phist[HROWS][HPAD];   // p^s at row 31+s
  __shared__ float ehist[HROWS][HPAD];   // e^s at row 31+s
  __shared__ float wrtL[HPAD];           // current W_r[:,b]
  __shared__ __align__(16) float hsS[NN];
  __shared__ float ldsB[64][5];          // dist-reduce partials (pad 5)
  __shared__ float ldsF[64];             // finalized dots: [0..30]=beta, [31..61]=delta, 62=|h|^2, 63=ssum
  __shared__ float cS[64];               // c_s at [32+s], zeros below
  __shared__ float rS[64];               // rden_s at [32+s], zeros below
  __shared__ float xwS[NT];
  __shared__ float redC[1][NW];

  // ---- zero-init history arrays (incl. the 31 zero-prefix rows) ----
  for (int i = tid; i < HROWS * HPAD; i += BLK) {
    (&khist[0][0])[i] = 0.f; (&phist[0][0])[i] = 0.f; (&ehist[0][0])[i] = 0.f;
  }
  if (tid < 64) { cS[tid] = 0.f; rS[tid] = 0.f; }

  // xw[t] = (x_t @ W_in)[b] via wave0
  if (w == 0) {
    const float wv = Win[l * NN + b];
    float c[NT];
    #pragma unroll
    for (int t2 = 0; t2 < NT; ++t2) c[t2] = x[t2 * NIN + l] * wv;
    #pragma unroll
    for (int o = 32; o > 0; o >>= 1) {
      #pragma unroll
      for (int t2 = 0; t2 < NT; ++t2) c[t2] += __shfl_xor(c[t2], o, 64);
    }
    if (l == 0) {
      #pragma unroll
      for (int t2 = 0; t2 < NT; ++t2) xwS[t2] = c[t2];
    }
  }

  float wrt   = Wrec[tid * NN + b];   // W_rec[tid][b], kept current locally
  float y_cur = y[tid];
  const float alP = Pout[0];          // P_output = alP * I
  const float alG = Pgg[0];           // each P_GG slice = alG * I
  float a_run = a0[b];
  wrtL[tid] = wrt;

  // ---- prologue: h_0 ----
  {
    const float s0 = block_reduce1(tanh_fast(a0[tid]) * wrt, redC, w, l); // fences init
    a_run = 0.9f * a_run + 0.1f * (s0 + xwS[0]);
    if (tid == 0) publish(&ws->hslot[b], pack_h(tanh_fast(a_run), 1u));
  }

  const int qq    = tid & 63;
  const int chunk = tid >> 6;

  #pragma unroll 1
  for (int t = 0; t < NT; ++t) {
    // ---- the ONLY global exchange: poll h_t ----
    const float h_own = poll_h(&ws->hslot[tid], (u32)(t + 1));
    hsS[tid] = h_own;
    __syncthreads();                           // barrier A

    // ---- z0 = W_o^0[:,tid].h — L2-streamed; consumed only after CORR ----
    const float4* h4 = (const float4*)hsS;
    float4 zac = make_float4(0.f, 0.f, 0.f, 0.f);
    #define Z0M(r) { const float4 hv = h4[r]; \
                     zac.x += Wout[(4*(r)+0)*NN+tid]*hv.x; \
                     zac.y += Wout[(4*(r)+1)*NN+tid]*hv.y; \
                     zac.z += Wout[(4*(r)+2)*NN+tid]*hv.z; \
                     zac.w += Wout[(4*(r)+3)*NN+tid]*hv.w; }
    REP48(Z0M)

    // ---- distributed reduce: 64 dots (31 betas, 31 deltas, |h|^2, ssum) ----
    {
      const float* hr;
      if      (qq < 31)  hr = &khist[30 + t - qq][0];   // beta_{qq+1}
      else if (qq < 62)  hr = &phist[61 + t - qq][0];   // delta_{qq-30}
      else if (qq == 62) hr = &hsS[0];                  // |h|^2
      else               hr = &wrtL[0];                 // ssum = h . W_r^{t-1}
      const int off = chunk * 64;
      float p0 = 0.f, p1 = 0.f, p2 = 0.f, p3 = 0.f;
      #pragma unroll
      for (int i = 0; i < 64; i += 4) {
        p0 = fmaf(hr[off + i + 0], hsS[off + i + 0], p0);
        p1 = fmaf(hr[off + i + 1], hsS[off + i + 1], p1);
        p2 = fmaf(hr[off + i + 2], hsS[off + i + 2], p2);
        p3 = fmaf(hr[off + i + 3], hsS[off + i + 3], p3);
      }
      ldsB[qq][chunk] = (p0 + p1) + (p2 + p3);
    }
    __syncthreads();                           // barrier B
    if (tid < 64) ldsF[tid] = ldsB[tid][0] + ldsB[tid][1] + ldsB[tid][2];
    __syncthreads();                           // barrier C

    // ---- history corrections: ALL addresses affine, j literal -> imm offsets ----
    const float hh   = ldsF[62];
    const float ssum = ldsF[63];
    float kacc = alP * h_own, hk  = alP * hh;
    float pacc = alG * h_own, hPh = alG * hh;
    float zcor = 0.f;
    #define CORR(j) { const float bj = ldsF[(j)-1]; const float gj = cS[32+t-(j)] * bj; \
                      kacc = fmaf(-gj, khist[31+t-(j)][tid], kacc); hk = fmaf(-gj, bj, hk); \
                      zcor = fmaf( gj, ehist[31+t-(j)][tid], zcor); \
                      const float dj = ldsF[30+(j)]; const float rj = rS[32+t-(j)] * dj; \
                      pacc = fmaf(-rj, phist[31+t-(j)][tid], pacc); hPh = fmaf(-rj, dj, hPh); }
    REP31(CORR)

    const float zc    = (((zac.x + zac.y) + (zac.z + zac.w))) - zcor;
    const float c_t   = 1.f / (1.f + hk);      // global (identical in all blocks)
    const float rden  = 1.f / (1.f + hPh);     // per-block (slice b)
    const float e_own = zc - y_cur;

    if (b == 0) out[t * NN + tid] = zc;        // z IS the output row
    if (t == NT - 1) break;

    if (tid == 0) { cS[32 + t] = c_t; rS[32 + t] = rden; }

    // ---- corr2 = sum_i h_i p_i e_i ----
    const float corr2 = block_reduce1(h_own * pacc * e_own, redC, w, l);  // barrier D

    a_run = 0.9f * a_run + 0.1f * (ssum - rden * corr2 + xwS[t + 1]);
    if (tid == 0) publish(&ws->hslot[b], pack_h(tanh_fast(a_run), (u32)(t + 2)));

    // ---- off-critical-path: history writes at row 31+t (fenced by next A) ----
    khist[31 + t][tid] = kacc;
    phist[31 + t][tid] = pacc;
    ehist[31 + t][tid] = e_own;
    wrt = fmaf(-rden * pacc, e_own, wrt);      // W_r[tid][b] -= rden p_tid e_tid
    wrtL[tid] = wrt;
    y_cur = y[(t + 1) * NN + tid];
  }
}

extern "C" void kernel_launch(void* const* d_in, const int* in_sizes, int n_in,
                              void* d_out, int out_size, void* d_ws, size_t ws_size,
                              hipStream_t stream) {
  const float* x    = (const float*)d_in[0];
  const float* y    = (const float*)d_in[1];
  const float* Win  = (const float*)d_in[2];
  const float* Wrec = (const float*)d_in[3];
  const float* Wout = (const float*)d_in[4];
  const float* a0   = (const float*)d_in[5];
  const float* Pout = (const float*)d_in[6];
  const float* Pgg  = (const float*)d_in[7];
  float* out = (float*)d_out;
  WS* ws = (WS*)d_ws;
  (void)in_sizes; (void)n_in; (void)out_size; (void)ws_size;

  // reset h tags each call (graph replays must not see stale tags)
  hipMemsetAsync(ws, 0, sizeof(WS), stream);
  force_persistent<<<NN, BLK, 0, stream>>>(x, y, Win, Wrec, Wout, a0, Pout, Pgg, out, ws);
}